// Round 4
// baseline (418.486 us; speedup 1.0000x reference)
//
#include <hip/hip_runtime.h>
#include <hip/hip_bf16.h>
#include <cstdint>
#include <cstddef>

#define NTOK 32768
#define DIN 512
#define EDIM_ 256
#define HID 1024
#define NEXP 4

typedef __attribute__((ext_vector_type(8))) short short8;
typedef __attribute__((ext_vector_type(16))) float f32x16;
typedef __attribute__((ext_vector_type(4))) unsigned short u16x4;

typedef __attribute__((address_space(1))) const void gv_t;
typedef __attribute__((address_space(3))) void lv_t;

// ---- workspace layout (bytes) ----
#define OFF_COUNTS 0
#define OFF_GVAL   256
#define OFF_PERM   (OFF_GVAL + 131072)
#define OFF_PART   (OFF_PERM + 524288)
#define OFF_WB1    (OFF_PART + 40960)
#define OFF_WB2    (OFF_WB1 + 4194304)

__device__ __forceinline__ unsigned short f2bf(float f) {
  unsigned u = __float_as_uint(f);
  u = (u + 0x7fffu + ((u >> 16) & 1u)) >> 16;
  return (unsigned short)u;
}

__device__ __forceinline__ f32x16 mfma32(short8 a, short8 b, f32x16 c) {
  return __builtin_amdgcn_mfma_f32_32x32x16_bf16(a, b, c, 0, 0, 0);
}

// ---------------- router + cvt fused ----------------
__global__ __launch_bounds__(256) void router_kernel(const float* __restrict__ x,
                                                     const float* __restrict__ emb,
                                                     const float* __restrict__ rw,
                                                     float* __restrict__ gval,
                                                     unsigned* __restrict__ counts,
                                                     unsigned* __restrict__ perm,
                                                     double* __restrict__ partials,
                                                     const float4* __restrict__ w1f,
                                                     const float4* __restrict__ w2f,
                                                     unsigned short* __restrict__ wb1,
                                                     unsigned short* __restrict__ wb2) {
  // --- weight cvt: 4 float4-pairs per thread (512 blocks x 256 thr x 4) ---
#pragma unroll
  for (int c = 0; c < 4; c++) {
    const int i = blockIdx.x * 1024 + c * 256 + threadIdx.x;
    float4 a = w1f[i];
    float4 b = w2f[i];
    u16x4 pa, pb;
    pa[0] = f2bf(a.x); pa[1] = f2bf(a.y); pa[2] = f2bf(a.z); pa[3] = f2bf(a.w);
    pb[0] = f2bf(b.x); pb[1] = f2bf(b.y); pb[2] = f2bf(b.z); pb[3] = f2bf(b.w);
    *(u16x4*)(wb1 + (size_t)i * 4) = pa;
    *(u16x4*)(wb2 + (size_t)i * 4) = pb;
  }

  __shared__ double vals[64][5];
  __shared__ int sgid[64];
  const int wave = threadIdx.x >> 6, lane = threadIdx.x & 63;

  // per-lane router weights in registers: rw is [768][4] row-major
  float4 rwe[4], rwx[8];
#pragma unroll
  for (int i = 0; i < 4; ++i) rwe[i] = *(const float4*)(rw + (lane * 4 + i) * 4);
#pragma unroll
  for (int i = 0; i < 8; ++i) rwx[i] = *(const float4*)(rw + (256 + lane * 8 + i) * 4);

  for (int it = 0; it < 16; it++) {
    const int sl = wave * 16 + it;
    const int t = blockIdx.x * 64 + sl;
    const float4 e4 = *(const float4*)(emb + (size_t)t * EDIM_ + lane * 4);
    const float4 x0 = *(const float4*)(x + (size_t)t * DIN + lane * 8);
    const float4 x1 = *(const float4*)(x + (size_t)t * DIN + lane * 8 + 4);
    const float ev[4] = {e4.x, e4.y, e4.z, e4.w};
    const float xv[8] = {x0.x, x0.y, x0.z, x0.w, x1.x, x1.y, x1.z, x1.w};
    double a0 = 0, a1 = 0, a2 = 0, a3 = 0;
#pragma unroll
    for (int i = 0; i < 4; ++i) {
      a0 += (double)ev[i] * rwe[i].x; a1 += (double)ev[i] * rwe[i].y;
      a2 += (double)ev[i] * rwe[i].z; a3 += (double)ev[i] * rwe[i].w;
    }
#pragma unroll
    for (int i = 0; i < 8; ++i) {
      a0 += (double)xv[i] * rwx[i].x; a1 += (double)xv[i] * rwx[i].y;
      a2 += (double)xv[i] * rwx[i].z; a3 += (double)xv[i] * rwx[i].w;
    }
    for (int off = 32; off > 0; off >>= 1) {
      a0 += __shfl_down(a0, off); a1 += __shfl_down(a1, off);
      a2 += __shfl_down(a2, off); a3 += __shfl_down(a3, off);
    }
    if (lane == 0) {
      double l[4] = {a0, a1, a2, a3};
      int bi = 0; double mx = l[0];
      for (int k = 1; k < 4; k++) if (l[k] > mx) { mx = l[k]; bi = k; }
      double p[4], s = 0;
      for (int k = 0; k < 4; k++) { p[k] = exp(l[k] - mx); s += p[k]; }
      double inv = 1.0 / s, sq = 0, sp = 0;
      for (int k = 0; k < 4; k++) { p[k] *= inv; sq += p[k] * p[k]; sp += p[k]; }
      gval[t] = (float)p[bi];
      sgid[sl] = bi;
      double* vv = vals[sl];
      vv[0] = p[0]; vv[1] = p[1]; vv[2] = p[2]; vv[3] = p[3];
      vv[4] = sp / (sqrt(sq) + 1e-10);
    }
  }
  __syncthreads();
  if (threadIdx.x < 5) {
    double acc = 0;
    for (int k = 0; k < 64; k++) acc += vals[k][threadIdx.x];
    partials[(size_t)blockIdx.x * 5 + threadIdx.x] = acc;
  }
  if (threadIdx.x < 64) {  // wave 0: scatter 64 tokens
    const int e = sgid[threadIdx.x];
    const int t = blockIdx.x * 64 + threadIdx.x;
    for (int ei = 0; ei < NEXP; ei++) {
      unsigned long long mask = __ballot(e == ei);
      if (mask == 0ull) continue;
      const int leader = __ffsll((unsigned long long)mask) - 1;
      unsigned base = 0;
      if (lane == leader) base = atomicAdd(&counts[ei], (unsigned)__popcll(mask));
      base = __shfl(base, leader, 64);
      if (e == ei) {
        const int rank = __popcll(mask & ((1ull << lane) - 1ull));
        perm[(size_t)ei * NTOK + base + rank] = (unsigned)t;
      }
    }
  }
}

// ---------------- fused grouped expert FFN: 32x32x16 MFMA, conflict-free LDS ----------------
// LDS: Xs [64 r][256 k] bf16 @0 (32KB)   8-row-group subtiles, slot XOR (r&7)^(g&7)
//      Hs [64 r][512 h] bf16 @32768 (64KB)  same scheme
//      W bufs 3 x 16KB @98304: tile [512n][16k], addr16 = (n>>3)*16 + kh*8 + (n&7)
//      toks u32[64] @147456, gvals f32[64] @147712 -> total 147968
#define LDS_HS 32768
#define LDS_BUF 98304
#define LDS_TOK 147456
#define LDS_GVL 147712
#define LDS_TOTAL 147968

__global__ __launch_bounds__(512, 2) void ffn_kernel(
    const float* __restrict__ x,
    const float* __restrict__ b1, const float* __restrict__ b2,
    const unsigned short* __restrict__ wb1, const unsigned short* __restrict__ wb2,
    const unsigned* __restrict__ counts, const unsigned* __restrict__ perm,
    const float* __restrict__ gval, const double* __restrict__ partials,
    float* __restrict__ out) {
  extern __shared__ char smem[];
  char* Xs = smem;
  char* Hs = smem + LDS_HS;
  char* bufs = smem + LDS_BUF;
  unsigned* toksL = (unsigned*)(smem + LDS_TOK);
  float* gvalsL = (float*)(smem + LDS_GVL);

  const int tid = threadIdx.x;
  const int lane = tid & 63, wid = tid >> 6;
  const int lane31 = lane & 31, lh = lane >> 5;

  const unsigned c0 = counts[0], c1 = counts[1], c2 = counts[2], c3 = counts[3];
  const unsigned n0 = (c0 + 63u) >> 6, n1 = (c1 + 63u) >> 6, n2 = (c2 + 63u) >> 6, n3 = (c3 + 63u) >> 6;
  const unsigned bs1 = n0, bs2 = n0 + n1, bs3 = n0 + n1 + n2, total = bs3 + n3;

  // XCD-bijective swizzle for nwg=516 (q=64, r=4)
  const unsigned orig = blockIdx.x;
  const unsigned xcd = orig & 7u, jj0 = orig >> 3;
  const unsigned wg = (xcd < 4u ? xcd * 65u : 260u + (xcd - 4u) * 64u) + jj0;

  // loss finalize (block 0, wave 0)
  if (orig == 0u && wid == 0) {
    double s0 = 0, s1 = 0, s2 = 0, s3 = 0, s4 = 0;
    for (int k = lane; k < 512; k += 64) {
      const double* p = partials + (size_t)k * 5;
      s0 += p[0]; s1 += p[1]; s2 += p[2]; s3 += p[3]; s4 += p[4];
    }
    for (int off = 32; off > 0; off >>= 1) {
      s0 += __shfl_down(s0, off); s1 += __shfl_down(s1, off);
      s2 += __shfl_down(s2, off); s3 += __shfl_down(s3, off);
      s4 += __shfl_down(s4, off);
    }
    if (lane == 0) {
      double mean = (s0 + s1 + s2 + s3) * 0.25;
      double var = ((s0 - mean) * (s0 - mean) + (s1 - mean) * (s1 - mean) +
                    (s2 - mean) * (s2 - mean) + (s3 - mean) * (s3 - mean)) * 0.25;
      out[16777216] = (float)(s4 / (double)NTOK);
      out[16777217] = (float)(var / (mean * mean + 1e-10));
    }
  }

  if (wg >= total) return;
  int e; unsigned tb;
  if (wg >= bs3)      { e = 3; tb = bs3; }
  else if (wg >= bs2) { e = 2; tb = bs2; }
  else if (wg >= bs1) { e = 1; tb = bs1; }
  else                { e = 0; tb = 0;   }
  const unsigned cnt_e = (e == 0) ? c0 : (e == 1) ? c1 : (e == 2) ? c2 : c3;
  const unsigned trow0 = (wg - tb) * 64u;
  const int mcnt = (int)min(64u, cnt_e - trow0);
  const size_t pbase = (size_t)e * NTOK + trow0;

  const unsigned short* w1e = wb1 + (size_t)e * HID * DIN;
  const unsigned short* w2e = wb2 + (size_t)e * DIN * HID;

  // issue one 16KB W tile (2 x global_load_lds(16B)/thread), tile u in [0,128)
  auto issueW = [&](int u, char* dst) {
    const int pu = u >> 6, ru = u & 63;
#pragma unroll
    for (int pp = 0; pp < 2; ++pp) {
      const int L = pp * 512 + wid * 64 + lane;
      const int ng = L >> 4, rem = L & 15;
      const int kk = rem >> 3, nl = rem & 7;
      const int n = ng * 8 + nl;
      const unsigned short* g;
      if (ru < 32) g = w1e + ((size_t)(pu * 512 + n)) * 512 + ru * 16 + kk * 8;
      else         g = w2e + (size_t)n * 1024 + pu * 512 + (ru - 32) * 16 + kk * 8;
      __builtin_amdgcn_global_load_lds((gv_t*)g, (lv_t*)(dst + pp * 8192 + wid * 1024), 16, 0, 0);
    }
  };

  // stage tokens/gates
  if (tid < 64) {
    const int rr2 = tid < mcnt ? tid : (mcnt - 1);
    const unsigned tok = perm[pbase + rr2];
    toksL[tid] = tok;
    gvalsL[tid] = gval[tok];
  }
  __syncthreads();

  // b1/b2 per-lane preload
  float b1v0[2], b1v1[2];
#pragma unroll
  for (int nf = 0; nf < 2; ++nf) {
    const int cc = wid * 64 + nf * 32 + lane31;
    b1v0[nf] = b1[e * HID + cc];
    b1v1[nf] = b1[e * HID + 512 + cc];
  }

  // X restage: wave w stages chunks g = w*4..w*4+3 of all 64 rows (rr = lane)
  auto restageX = [&](int kh, int issueU, char* ibuf) {
    const unsigned tok = toksL[lane];
    const float* srcx = x + (size_t)tok * DIN + kh * 256 + wid * 32;
    float4 fx[8];
#pragma unroll
    for (int i = 0; i < 8; ++i) fx[i] = *(const float4*)(srcx + i * 4);
    asm volatile("" ::: "memory");
    if (issueU >= 0) issueW(issueU, ibuf);
#pragma unroll
    for (int i = 0; i < 4; ++i) {
      const int g = wid * 4 + i;
      short8 v;
      v[0] = (short)f2bf(fx[2 * i].x); v[1] = (short)f2bf(fx[2 * i].y);
      v[2] = (short)f2bf(fx[2 * i].z); v[3] = (short)f2bf(fx[2 * i].w);
      v[4] = (short)f2bf(fx[2 * i + 1].x); v[5] = (short)f2bf(fx[2 * i + 1].y);
      v[6] = (short)f2bf(fx[2 * i + 1].z); v[7] = (short)f2bf(fx[2 * i + 1].w);
      *(short8*)(Xs + ((lane >> 3) << 12) + g * 128 + ((((unsigned)lane & 7u) ^ ((unsigned)g & 7u)) << 4)) = v;
    }
  };

  // prologue: stage Xs(kh0), prefetch W0,W1
  restageX(0, -1, nullptr);
  issueW(0, bufs);
  issueW(1, bufs + 16384);
  asm volatile("s_waitcnt lgkmcnt(0)" ::: "memory");
  __builtin_amdgcn_s_barrier();

  f32x16 acc1[2][2];
  f32x16 acc2[2][2];
#pragma unroll
  for (int i = 0; i < 2; i++)
#pragma unroll
    for (int j = 0; j < 2; j++) acc2[i][j] = f32x16{};

  int m3 = 0;
  for (int t = 0; t < 128; ++t) {
    if (t == 127) asm volatile("s_waitcnt vmcnt(0)" ::: "memory");
    else          asm volatile("s_waitcnt vmcnt(2)" ::: "memory");
    __builtin_amdgcn_s_barrier();

    const int p = t >> 6, r = t & 63;
    const int iPrev = (m3 == 0) ? 2 : m3 - 1;
    char* bufI = bufs + iPrev * 16384;
    char* bufC = bufs + m3 * 16384;

    if (r == 0) {
#pragma unroll
      for (int i = 0; i < 2; i++)
#pragma unroll
        for (int j = 0; j < 2; j++) acc1[i][j] = f32x16{};
    }

    if (t == 16 || t == 64 || t == 80) {
      restageX((r >> 4) & 1, t + 2, bufI);
      asm volatile("s_waitcnt lgkmcnt(0)" ::: "memory");
      __builtin_amdgcn_s_barrier();
    } else {
      if (t + 2 < 128) issueW(t + 2, bufI);
    }

    if (r < 32) {
      // GEMM1 k-tile: acc1 += X[:, k16] * W1tile^T
      const int k16 = r & 15;
      const int gA = k16 * 2 + lh;
      const unsigned aoff = ((unsigned)(lane31 >> 3) << 12) + (unsigned)gA * 128 +
                            ((((unsigned)lane31 & 7u) ^ ((unsigned)gA & 7u)) << 4);
      short8 a0 = *(const short8*)(Xs + aoff);
      short8 a1 = *(const short8*)(Xs + aoff + 16384);
      const int nn = wid * 64 + lane31;
      const unsigned boff = ((unsigned)(nn >> 3) << 8) + ((unsigned)lh << 7) + (((unsigned)nn & 7u) << 4);
      short8 b0 = *(const short8*)(bufC + boff);
      short8 b1f = *(const short8*)(bufC + boff + 1024);
      __builtin_amdgcn_s_setprio(1);
      acc1[0][0] = mfma32(a0, b0, acc1[0][0]);
      acc1[0][1] = mfma32(a0, b1f, acc1[0][1]);
      acc1[1][0] = mfma32(a1, b0, acc1[1][0]);
      acc1[1][1] = mfma32(a1, b1f, acc1[1][1]);
      __builtin_amdgcn_s_setprio(0);

      if (r == 31) {
        // bias + relu -> Hs
#pragma unroll
        for (int nf = 0; nf < 2; ++nf) {
          const int C = wid * 64 + nf * 32 + lane31;
          const int gC = C >> 3;
          const float bias = p ? b1v1[nf] : b1v0[nf];
          const unsigned cbase = (unsigned)gC * 128 + (((unsigned)C & 7u) << 1);
#pragma unroll
          for (int v = 0; v < 16; ++v) {
            const int Rb = (v & 3) + 8 * (v >> 2) + 4 * lh;
#pragma unroll
            for (int mf = 0; mf < 2; ++mf) {
              const int R = Rb + mf * 32;
              float val = acc1[mf][nf][v] + bias;
              val = val > 0.f ? val : 0.f;
              *(unsigned short*)(Hs + ((unsigned)(R >> 3) << 13) +
                                 ((((unsigned)R & 7u) ^ ((unsigned)gC & 7u)) << 4) + cbase) = f2bf(val);
            }
          }
        }
        asm volatile("s_waitcnt lgkmcnt(0)" ::: "memory");
      }
    } else {
      // GEMM2 k-tile: acc2 += Hs[:, k16] * W2tile^T
      const int j = r - 32;
      const int gH = j * 2 + lh;
      const unsigned aoff = ((unsigned)(lane31 >> 3) << 13) + (unsigned)gH * 128 +
                            ((((unsigned)lane31 & 7u) ^ ((unsigned)gH & 7u)) << 4);
      short8 a0 = *(const short8*)(Hs + aoff);
      short8 a1 = *(const short8*)(Hs + aoff + 32768);
      const int nn = wid * 64 + lane31;
      const unsigned boff = ((unsigned)(nn >> 3) << 8) + ((unsigned)lh << 7) + (((unsigned)nn & 7u) << 4);
      short8 b0 = *(const short8*)(bufC + boff);
      short8 b1f = *(const short8*)(bufC + boff + 1024);
      __builtin_amdgcn_s_setprio(1);
      acc2[0][0] = mfma32(a0, b0, acc2[0][0]);
      acc2[0][1] = mfma32(a0, b1f, acc2[0][1]);
      acc2[1][0] = mfma32(a1, b0, acc2[1][0]);
      acc2[1][1] = mfma32(a1, b1f, acc2[1][1]);
      __builtin_amdgcn_s_setprio(0);
    }
    m3 = (m3 == 2) ? 0 : m3 + 1;
  }

  // epilogue: (y + b2) * gate -> out
  const float* b2e = b2 + e * DIN;
#pragma unroll
  for (int nf = 0; nf < 2; ++nf) {
    const int d = wid * 64 + nf * 32 + lane31;
    const float bv = b2e[d];
#pragma unroll
    for (int v = 0; v < 16; ++v) {
      const int Rb = (v & 3) + 8 * (v >> 2) + 4 * lh;
#pragma unroll
      for (int mf = 0; mf < 2; ++mf) {
        const int R = Rb + mf * 32;
        if (R < mcnt) {
          const unsigned tok = toksL[R];
          out[(size_t)tok * DIN + d] = (acc2[mf][nf][v] + bv) * gvalsL[R];
        }
      }
    }
  }
}

extern "C" void kernel_launch(void* const* d_in, const int* in_sizes, int n_in,
                              void* d_out, int out_size, void* d_ws, size_t ws_size,
                              hipStream_t stream) {
  const float* x   = (const float*)d_in[0];
  const float* emb = (const float*)d_in[1];
  const float* rw  = (const float*)d_in[2];
  const float* w1  = (const float*)d_in[3];
  const float* b1  = (const float*)d_in[4];
  const float* w2  = (const float*)d_in[5];
  const float* b2  = (const float*)d_in[6];
  float* out = (float*)d_out;

  char* ws = (char*)d_ws;
  unsigned* counts = (unsigned*)(ws + OFF_COUNTS);
  float* gval = (float*)(ws + OFF_GVAL);
  unsigned* perm = (unsigned*)(ws + OFF_PERM);
  double* partials = (double*)(ws + OFF_PART);
  unsigned short* wb1 = (unsigned short*)(ws + OFF_WB1);
  unsigned short* wb2 = (unsigned short*)(ws + OFF_WB2);

  hipMemsetAsync(ws, 0, 256, stream);
  router_kernel<<<512, 256, 0, stream>>>(x, emb, rw, gval, counts, perm, partials,
                                         (const float4*)w1, (const float4*)w2, wb1, wb2);

  hipFuncSetAttribute((const void*)ffn_kernel, hipFuncAttributeMaxDynamicSharedMemorySize, LDS_TOTAL);
  ffn_kernel<<<516, 512, LDS_TOTAL, stream>>>(x, b1, b2, wb1, wb2, counts, perm, gval, partials, out);
}

// Round 5
// 214.196 us; speedup vs baseline: 1.9538x; 1.9538x over previous
//
#include <hip/hip_runtime.h>
#include <hip/hip_bf16.h>
#include <cstdint>
#include <cstddef>

#define NTOK 32768
#define DIN 512
#define EDIM_ 256
#define HID 1024
#define NEXP 4

typedef __attribute__((ext_vector_type(8))) short short8;
typedef __attribute__((ext_vector_type(16))) float f32x16;

// ---- workspace layout (bytes) ----
#define OFF_COUNTS 0
#define OFF_GVAL   256
#define OFF_PERM   (OFF_GVAL + 131072)
#define OFF_PART   (OFF_PERM + 524288)
#define OFF_WB1    (OFF_PART + 40960)
#define OFF_WB2    (OFF_WB1 + 4194304)

__device__ __forceinline__ unsigned short f2bf(float f) {
  unsigned u = __float_as_uint(f);
  u = (u + 0x7fffu + ((u >> 16) & 1u)) >> 16;
  return (unsigned short)u;
}

__device__ __forceinline__ f32x16 mfma32(short8 a, short8 b, f32x16 c) {
  return __builtin_amdgcn_mfma_f32_32x32x16_bf16(a, b, c, 0, 0, 0);
}

__device__ __forceinline__ short8 pack8(float4 f0, float4 f1) {
  short8 v;
  v[0] = (short)f2bf(f0.x); v[1] = (short)f2bf(f0.y);
  v[2] = (short)f2bf(f0.z); v[3] = (short)f2bf(f0.w);
  v[4] = (short)f2bf(f1.x); v[5] = (short)f2bf(f1.y);
  v[6] = (short)f2bf(f1.z); v[7] = (short)f2bf(f1.w);
  return v;
}

// ---------------- router + W pack fused ----------------
// Packs W1/W2 into MFMA B-fragment order:
//  pw1[e][nb(32)][k16(32)][lane(64)*16B]  element: W1[e][nb*32+(l&31)][k16*16+8*(l>>5)+j]
//  pw2[e][nb(16)][k16(64)][lane(64)*16B]  element: W2[e][nb*32+(l&31)][k16*16+8*(l>>5)+j]
__global__ __launch_bounds__(256) void router_kernel(const float* __restrict__ x,
                                                     const float* __restrict__ emb,
                                                     const float* __restrict__ rw,
                                                     float* __restrict__ gval,
                                                     unsigned* __restrict__ counts,
                                                     unsigned* __restrict__ perm,
                                                     double* __restrict__ partials,
                                                     const float* __restrict__ w1,
                                                     const float* __restrict__ w2,
                                                     char* __restrict__ pw1,
                                                     char* __restrict__ pw2) {
  // --- W pack: 4 fragments-slots per thread (512 blocks x 256 thr x 4 = 524288 units) ---
#pragma unroll
  for (int c = 0; c < 4; c++) {
    const unsigned u = (unsigned)blockIdx.x * 1024u + (unsigned)c * 256u + threadIdx.x;
    const unsigned m = u >> 18, u18 = u & 0x3FFFFu;
    const unsigned e = u18 >> 16, l = u18 & 63u;
    const float* s;
    if (m == 0) {
      const unsigned nb = (u18 >> 11) & 31u, k16 = (u18 >> 6) & 31u;
      s = w1 + ((size_t)((e << 10) + (nb << 5) + (l & 31u)) << 9) + (k16 << 4) + ((l >> 5) << 3);
    } else {
      const unsigned nb = (u18 >> 12) & 15u, k16 = (u18 >> 6) & 63u;
      s = w2 + ((size_t)((e << 9) + (nb << 5) + (l & 31u)) << 10) + (k16 << 4) + ((l >> 5) << 3);
    }
    float4 f0 = *(const float4*)s;
    float4 f1 = *(const float4*)(s + 4);
    short8 v = pack8(f0, f1);
    *(short8*)((m == 0 ? pw1 : pw2) + ((size_t)u18 << 4)) = v;
  }

  __shared__ double vals[64][5];
  __shared__ int sgid[64];
  const int wave = threadIdx.x >> 6, lane = threadIdx.x & 63;

  // per-lane router weights in registers: rw is [768][4] row-major
  float4 rwe[4], rwx[8];
#pragma unroll
  for (int i = 0; i < 4; ++i) rwe[i] = *(const float4*)(rw + (lane * 4 + i) * 4);
#pragma unroll
  for (int i = 0; i < 8; ++i) rwx[i] = *(const float4*)(rw + (256 + lane * 8 + i) * 4);

  for (int it = 0; it < 16; it++) {
    const int sl = wave * 16 + it;
    const int t = blockIdx.x * 64 + sl;
    const float4 e4 = *(const float4*)(emb + (size_t)t * EDIM_ + lane * 4);
    const float4 x0 = *(const float4*)(x + (size_t)t * DIN + lane * 8);
    const float4 x1 = *(const float4*)(x + (size_t)t * DIN + lane * 8 + 4);
    const float ev[4] = {e4.x, e4.y, e4.z, e4.w};
    const float xv[8] = {x0.x, x0.y, x0.z, x0.w, x1.x, x1.y, x1.z, x1.w};
    double a0 = 0, a1 = 0, a2 = 0, a3 = 0;
#pragma unroll
    for (int i = 0; i < 4; ++i) {
      a0 += (double)ev[i] * rwe[i].x; a1 += (double)ev[i] * rwe[i].y;
      a2 += (double)ev[i] * rwe[i].z; a3 += (double)ev[i] * rwe[i].w;
    }
#pragma unroll
    for (int i = 0; i < 8; ++i) {
      a0 += (double)xv[i] * rwx[i].x; a1 += (double)xv[i] * rwx[i].y;
      a2 += (double)xv[i] * rwx[i].z; a3 += (double)xv[i] * rwx[i].w;
    }
    for (int off = 32; off > 0; off >>= 1) {
      a0 += __shfl_down(a0, off); a1 += __shfl_down(a1, off);
      a2 += __shfl_down(a2, off); a3 += __shfl_down(a3, off);
    }
    if (lane == 0) {
      double l[4] = {a0, a1, a2, a3};
      int bi = 0; double mx = l[0];
      for (int k = 1; k < 4; k++) if (l[k] > mx) { mx = l[k]; bi = k; }
      double p[4], s = 0;
      for (int k = 0; k < 4; k++) { p[k] = exp(l[k] - mx); s += p[k]; }
      double inv = 1.0 / s, sq = 0, sp = 0;
      for (int k = 0; k < 4; k++) { p[k] *= inv; sq += p[k] * p[k]; sp += p[k]; }
      gval[t] = (float)p[bi];
      sgid[sl] = bi;
      double* vv = vals[sl];
      vv[0] = p[0]; vv[1] = p[1]; vv[2] = p[2]; vv[3] = p[3];
      vv[4] = sp / (sqrt(sq) + 1e-10);
    }
  }
  __syncthreads();
  if (threadIdx.x < 5) {
    double acc = 0;
    for (int k = 0; k < 64; k++) acc += vals[k][threadIdx.x];
    partials[(size_t)blockIdx.x * 5 + threadIdx.x] = acc;
  }
  if (threadIdx.x < 64) {  // wave 0: scatter 64 tokens
    const int e = sgid[threadIdx.x];
    const int t = blockIdx.x * 64 + threadIdx.x;
    for (int ei = 0; ei < NEXP; ei++) {
      unsigned long long mask = __ballot(e == ei);
      if (mask == 0ull) continue;
      const int leader = __ffsll((unsigned long long)mask) - 1;
      unsigned base = 0;
      if (lane == leader) base = atomicAdd(&counts[ei], (unsigned)__popcll(mask));
      base = __shfl(base, leader, 64);
      if (e == ei) {
        const int rank = __popcll(mask & ((1ull << lane) - 1ull));
        perm[(size_t)ei * NTOK + base + rank] = (unsigned)t;
      }
    }
  }
}

// ---------------- fused grouped expert FFN: reg-B streaming, no W-LDS ----------------
// LDS: Xs 64KB (frag layout: unit(k16,mf)=1KB, slot-swizzled)
//      Hs 64KB (chunk of 512 hidden, same layout)
//      toks u32[64] @131072, gvals f32[64] @131328 -> total 131584
#define LDS_HS 65536
#define LDS_TOK 131072
#define LDS_GVL 131328
#define LDS_TOTAL 131584

__global__ __launch_bounds__(512, 1) void ffn_kernel(
    const float* __restrict__ x,
    const float* __restrict__ b1, const float* __restrict__ b2,
    const char* __restrict__ pw1, const char* __restrict__ pw2,
    const unsigned* __restrict__ counts, const unsigned* __restrict__ perm,
    const float* __restrict__ gval, const double* __restrict__ partials,
    float* __restrict__ out) {
  extern __shared__ char smem[];
  char* Xs = smem;
  char* Hs = smem + LDS_HS;
  unsigned* toksL = (unsigned*)(smem + LDS_TOK);
  float* gvalsL = (float*)(smem + LDS_GVL);

  const int tid = threadIdx.x;
  const int lane = tid & 63, wid = tid >> 6;
  const int l31 = lane & 31, lh = lane >> 5;
  // slot permutation: slot(kh, r) = (r>>2)<<3 | (r&3)<<1 | kh ; byte off = slot<<4
  const unsigned sloff = (unsigned)((((l31 >> 2) << 3) | ((l31 & 3) << 1) | lh) << 4);

  const unsigned c0 = counts[0], c1 = counts[1], c2 = counts[2], c3 = counts[3];
  const unsigned n0 = (c0 + 63u) >> 6, n1 = (c1 + 63u) >> 6, n2 = (c2 + 63u) >> 6, n3 = (c3 + 63u) >> 6;
  const unsigned bs1 = n0, bs2 = n0 + n1, bs3 = n0 + n1 + n2, total = bs3 + n3;

  // XCD swizzle for nwg=512 (q=64): contiguous 64-tile chunks per XCD
  const unsigned orig = blockIdx.x;
  const unsigned wg = (orig & 7u) * 64u + (orig >> 3);

  // loss finalize (block 0, wave 0)
  if (orig == 0u && wid == 0) {
    double s0 = 0, s1 = 0, s2 = 0, s3 = 0, s4 = 0;
    for (int k = lane; k < 512; k += 64) {
      const double* p = partials + (size_t)k * 5;
      s0 += p[0]; s1 += p[1]; s2 += p[2]; s3 += p[3]; s4 += p[4];
    }
    for (int off = 32; off > 0; off >>= 1) {
      s0 += __shfl_down(s0, off); s1 += __shfl_down(s1, off);
      s2 += __shfl_down(s2, off); s3 += __shfl_down(s3, off);
      s4 += __shfl_down(s4, off);
    }
    if (lane == 0) {
      double mean = (s0 + s1 + s2 + s3) * 0.25;
      double var = ((s0 - mean) * (s0 - mean) + (s1 - mean) * (s1 - mean) +
                    (s2 - mean) * (s2 - mean) + (s3 - mean) * (s3 - mean)) * 0.25;
      out[16777216] = (float)(s4 / (double)NTOK);
      out[16777217] = (float)(var / (mean * mean + 1e-10));
    }
  }

  for (unsigned ti = wg; ti < total; ti += 512u) {
    int e; unsigned tb;
    if (ti >= bs3)      { e = 3; tb = bs3; }
    else if (ti >= bs2) { e = 2; tb = bs2; }
    else if (ti >= bs1) { e = 1; tb = bs1; }
    else                { e = 0; tb = 0;   }
    const unsigned cnt_e = (e == 0) ? c0 : (e == 1) ? c1 : (e == 2) ? c2 : c3;
    const unsigned trow0 = (ti - tb) * 64u;
    const int mcnt = (int)min(64u, cnt_e - trow0);
    const size_t pbase = (size_t)e * NTOK + trow0;
    const char* pw1e = pw1 + ((size_t)e << 20);
    const char* pw2e = pw2 + ((size_t)e << 20);

    __builtin_amdgcn_s_barrier();   // prev tile fully consumed (epilogue/toksL/Xs/Hs)

    if (tid < 64) {
      const int rr = tid < mcnt ? tid : (mcnt - 1);
      const unsigned tok = perm[pbase + rr];
      toksL[tid] = tok;
      gvalsL[tid] = gval[tok];
    }
    // stage X: thread -> row r, col-chunks c = i*8+q (8 f32 each)
    {
      const int r = tid >> 3, q = tid & 7;
      const int rr = r < mcnt ? r : (mcnt - 1);
      const unsigned tok = perm[pbase + rr];
      const float* src = x + (size_t)tok * DIN + (q << 3);
#pragma unroll
      for (int i = 0; i < 8; ++i) {
        float4 f0 = *(const float4*)(src + (i << 6));
        float4 f1 = *(const float4*)(src + (i << 6) + 4);
        const int c = (i << 3) + q;
        const int k16 = c >> 1;
        unsigned sl = (unsigned)((((r & 31) >> 2) << 3) | ((r & 3) << 1) | (c & 1));
        sl ^= (unsigned)((k16 & 1) << 2);
        *(short8*)(Xs + (((k16 << 1) + (r >> 5)) << 10) + (sl << 4)) = pack8(f0, f1);
      }
    }
    asm volatile("s_waitcnt lgkmcnt(0)" ::: "memory");
    __builtin_amdgcn_s_barrier();

    f32x16 acc2[2][2];
#pragma unroll
    for (int i = 0; i < 2; i++)
#pragma unroll
      for (int j = 0; j < 2; j++) acc2[i][j] = f32x16{};

    for (int hc = 0; hc < 2; ++hc) {
      f32x16 acc1[2][2];
#pragma unroll
      for (int i = 0; i < 2; i++)
#pragma unroll
        for (int j = 0; j < 2; j++) acc1[i][j] = f32x16{};

      const float biasA = b1[e * HID + hc * 512 + wid * 64 + l31];
      const float biasB = b1[e * HID + hc * 512 + wid * 64 + 32 + l31];

      // ---- GEMM1: acc1 += X[64][512] * W1chunk^T ; B from global, depth-4 prefetch ----
      {
        const char* baseB1 = pw1e + ((size_t)(hc * 16 + wid * 2) << 15) + (lane << 4);
        short8 q0[4], q1[4];
#pragma unroll
        for (int j = 0; j < 4; ++j) {
          q0[j] = *(const short8*)(baseB1 + (j << 10));
          q1[j] = *(const short8*)(baseB1 + (1 << 15) + (j << 10));
        }
#pragma unroll
        for (int kk = 0; kk < 32; ++kk) {
          const unsigned xo = (unsigned)((kk & 1) << 6);
          short8 a0 = *(const short8*)(Xs + ((kk * 2 + 0) << 10) + (sloff ^ xo));
          short8 a1 = *(const short8*)(Xs + ((kk * 2 + 1) << 10) + (sloff ^ xo));
          short8 b0 = q0[kk & 3], b1f = q1[kk & 3];
          if (kk < 28) {
            q0[kk & 3] = *(const short8*)(baseB1 + ((kk + 4) << 10));
            q1[kk & 3] = *(const short8*)(baseB1 + (1 << 15) + ((kk + 4) << 10));
          }
          __builtin_amdgcn_s_setprio(1);
          acc1[0][0] = mfma32(a0, b0, acc1[0][0]);
          acc1[1][0] = mfma32(a1, b0, acc1[1][0]);
          acc1[0][1] = mfma32(a0, b1f, acc1[0][1]);
          acc1[1][1] = mfma32(a1, b1f, acc1[1][1]);
          __builtin_amdgcn_s_setprio(0);
        }
      }

      // ---- bias + relu -> Hs (frag layout) ----
#pragma unroll
      for (int mf = 0; mf < 2; ++mf)
#pragma unroll
        for (int nf = 0; nf < 2; ++nf) {
          const int nloc = wid * 64 + nf * 32 + l31;
          const int k16 = nloc >> 4;
          const unsigned kh = (unsigned)((nloc >> 3) & 1);
          const float bias = nf ? biasB : biasA;
          const unsigned base = (unsigned)(((k16 * 2 + mf) << 10) + ((l31 & 7) << 1));
          const unsigned xo = (unsigned)((k16 & 1) << 2);
#pragma unroll
          for (int v = 0; v < 16; ++v) {
            const int R31 = (v & 3) + 8 * (v >> 2) + 4 * lh;
            const unsigned sl = ((unsigned)(((R31 >> 2) << 3) | ((R31 & 3) << 1)) | kh) ^ xo;
            float val = acc1[mf][nf][v] + bias;
            val = val > 0.f ? val : 0.f;
            *(unsigned short*)(Hs + base + (sl << 4)) = f2bf(val);
          }
        }

      // prefetch GEMM2 B before the barrier (regs survive; latency hides under barrier)
      const char* baseB2 = pw2e + ((size_t)(wid * 2) << 16) + ((hc * 32) << 10) + (lane << 4);
      short8 r0[4], r1[4];
#pragma unroll
      for (int j = 0; j < 4; ++j) {
        r0[j] = *(const short8*)(baseB2 + (j << 10));
        r1[j] = *(const short8*)(baseB2 + (1 << 16) + (j << 10));
      }
      asm volatile("s_waitcnt lgkmcnt(0)" ::: "memory");
      __builtin_amdgcn_s_barrier();

      // ---- GEMM2: acc2 += H[64][512] * W2chunk^T ----
#pragma unroll
      for (int kk = 0; kk < 32; ++kk) {
        const unsigned xo = (unsigned)((kk & 1) << 6);
        short8 a0 = *(const short8*)(Hs + ((kk * 2 + 0) << 10) + (sloff ^ xo));
        short8 a1 = *(const short8*)(Hs + ((kk * 2 + 1) << 10) + (sloff ^ xo));
        short8 b0 = r0[kk & 3], b1f = r1[kk & 3];
        if (kk < 28) {
          r0[kk & 3] = *(const short8*)(baseB2 + ((kk + 4) << 10));
          r1[kk & 3] = *(const short8*)(baseB2 + (1 << 16) + ((kk + 4) << 10));
        }
        __builtin_amdgcn_s_setprio(1);
        acc2[0][0] = mfma32(a0, b0, acc2[0][0]);
        acc2[1][0] = mfma32(a1, b0, acc2[1][0]);
        acc2[0][1] = mfma32(a0, b1f, acc2[0][1]);
        acc2[1][1] = mfma32(a1, b1f, acc2[1][1]);
        __builtin_amdgcn_s_setprio(0);
      }
      asm volatile("s_waitcnt lgkmcnt(0)" ::: "memory");
      __builtin_amdgcn_s_barrier();   // Hs consumed; next chunk may overwrite
    }

    // ---- epilogue: (y + b2) * gate -> out ----
    const float* b2e = b2 + e * DIN;
#pragma unroll
    for (int nf = 0; nf < 2; ++nf) {
      const int d = wid * 64 + nf * 32 + l31;
      const float bv = b2e[d];
#pragma unroll
      for (int v = 0; v < 16; ++v) {
        const int Rb = (v & 3) + 8 * (v >> 2) + 4 * lh;
#pragma unroll
        for (int mf = 0; mf < 2; ++mf) {
          const int rt = Rb + mf * 32;
          if (rt < mcnt) {
            const unsigned tok = toksL[rt];
            out[(size_t)tok * DIN + d] = (acc2[mf][nf][v] + bv) * gvalsL[rt];
          }
        }
      }
    }
  }
}

extern "C" void kernel_launch(void* const* d_in, const int* in_sizes, int n_in,
                              void* d_out, int out_size, void* d_ws, size_t ws_size,
                              hipStream_t stream) {
  const float* x   = (const float*)d_in[0];
  const float* emb = (const float*)d_in[1];
  const float* rw  = (const float*)d_in[2];
  const float* w1  = (const float*)d_in[3];
  const float* b1  = (const float*)d_in[4];
  const float* w2  = (const float*)d_in[5];
  const float* b2  = (const float*)d_in[6];
  float* out = (float*)d_out;

  char* ws = (char*)d_ws;
  unsigned* counts = (unsigned*)(ws + OFF_COUNTS);
  float* gval = (float*)(ws + OFF_GVAL);
  unsigned* perm = (unsigned*)(ws + OFF_PERM);
  double* partials = (double*)(ws + OFF_PART);
  char* pw1 = ws + OFF_WB1;
  char* pw2 = ws + OFF_WB2;

  hipMemsetAsync(ws, 0, 256, stream);
  router_kernel<<<512, 256, 0, stream>>>(x, emb, rw, gval, counts, perm, partials,
                                         w1, w2, pw1, pw2);

  hipFuncSetAttribute((const void*)ffn_kernel, hipFuncAttributeMaxDynamicSharedMemorySize, LDS_TOTAL);
  ffn_kernel<<<512, 512, LDS_TOTAL, stream>>>(x, b1, b2, pw1, pw2, counts, perm, gval, partials, out);
}

// Round 6
// 182.366 us; speedup vs baseline: 2.2948x; 1.1745x over previous
//
#include <hip/hip_runtime.h>
#include <hip/hip_bf16.h>
#include <cstdint>
#include <cstddef>

#define NTOK 32768
#define DIN 512
#define EDIM_ 256
#define HID 1024
#define NEXP 4

typedef __attribute__((ext_vector_type(8))) short short8;
typedef __attribute__((ext_vector_type(16))) float f32x16;

// ---- workspace layout (bytes) ----
#define OFF_COUNTS 0
#define OFF_GVAL   256
#define OFF_PERM   (OFF_GVAL + 131072)
#define OFF_PART   (OFF_PERM + 524288)
#define OFF_WB1    (OFF_PART + 40960)
#define OFF_WB2    (OFF_WB1 + 4194304)

__device__ __forceinline__ unsigned short f2bf(float f) {
  unsigned u = __float_as_uint(f);
  u = (u + 0x7fffu + ((u >> 16) & 1u)) >> 16;
  return (unsigned short)u;
}

__device__ __forceinline__ f32x16 mfma32(short8 a, short8 b, f32x16 c) {
  return __builtin_amdgcn_mfma_f32_32x32x16_bf16(a, b, c, 0, 0, 0);
}

__device__ __forceinline__ short8 pack8(float4 f0, float4 f1) {
  short8 v;
  v[0] = (short)f2bf(f0.x); v[1] = (short)f2bf(f0.y);
  v[2] = (short)f2bf(f0.z); v[3] = (short)f2bf(f0.w);
  v[4] = (short)f2bf(f1.x); v[5] = (short)f2bf(f1.y);
  v[6] = (short)f2bf(f1.z); v[7] = (short)f2bf(f1.w);
  return v;
}

// ---------------- router + W pack fused (unchanged from R5, validated) ----------------
__global__ __launch_bounds__(256) void router_kernel(const float* __restrict__ x,
                                                     const float* __restrict__ emb,
                                                     const float* __restrict__ rw,
                                                     float* __restrict__ gval,
                                                     unsigned* __restrict__ counts,
                                                     unsigned* __restrict__ perm,
                                                     double* __restrict__ partials,
                                                     const float* __restrict__ w1,
                                                     const float* __restrict__ w2,
                                                     char* __restrict__ pw1,
                                                     char* __restrict__ pw2) {
#pragma unroll
  for (int c = 0; c < 4; c++) {
    const unsigned u = (unsigned)blockIdx.x * 1024u + (unsigned)c * 256u + threadIdx.x;
    const unsigned m = u >> 18, u18 = u & 0x3FFFFu;
    const unsigned e = u18 >> 16, l = u18 & 63u;
    const float* s;
    if (m == 0) {
      const unsigned nb = (u18 >> 11) & 31u, k16 = (u18 >> 6) & 31u;
      s = w1 + ((size_t)((e << 10) + (nb << 5) + (l & 31u)) << 9) + (k16 << 4) + ((l >> 5) << 3);
    } else {
      const unsigned nb = (u18 >> 12) & 15u, k16 = (u18 >> 6) & 63u;
      s = w2 + ((size_t)((e << 9) + (nb << 5) + (l & 31u)) << 10) + (k16 << 4) + ((l >> 5) << 3);
    }
    float4 f0 = *(const float4*)s;
    float4 f1 = *(const float4*)(s + 4);
    short8 v = pack8(f0, f1);
    *(short8*)((m == 0 ? pw1 : pw2) + ((size_t)u18 << 4)) = v;
  }

  __shared__ double vals[64][5];
  __shared__ int sgid[64];
  const int wave = threadIdx.x >> 6, lane = threadIdx.x & 63;

  float4 rwe[4], rwx[8];
#pragma unroll
  for (int i = 0; i < 4; ++i) rwe[i] = *(const float4*)(rw + (lane * 4 + i) * 4);
#pragma unroll
  for (int i = 0; i < 8; ++i) rwx[i] = *(const float4*)(rw + (256 + lane * 8 + i) * 4);

  for (int it = 0; it < 16; it++) {
    const int sl = wave * 16 + it;
    const int t = blockIdx.x * 64 + sl;
    const float4 e4 = *(const float4*)(emb + (size_t)t * EDIM_ + lane * 4);
    const float4 x0 = *(const float4*)(x + (size_t)t * DIN + lane * 8);
    const float4 x1 = *(const float4*)(x + (size_t)t * DIN + lane * 8 + 4);
    const float ev[4] = {e4.x, e4.y, e4.z, e4.w};
    const float xv[8] = {x0.x, x0.y, x0.z, x0.w, x1.x, x1.y, x1.z, x1.w};
    double a0 = 0, a1 = 0, a2 = 0, a3 = 0;
#pragma unroll
    for (int i = 0; i < 4; ++i) {
      a0 += (double)ev[i] * rwe[i].x; a1 += (double)ev[i] * rwe[i].y;
      a2 += (double)ev[i] * rwe[i].z; a3 += (double)ev[i] * rwe[i].w;
    }
#pragma unroll
    for (int i = 0; i < 8; ++i) {
      a0 += (double)xv[i] * rwx[i].x; a1 += (double)xv[i] * rwx[i].y;
      a2 += (double)xv[i] * rwx[i].z; a3 += (double)xv[i] * rwx[i].w;
    }
    for (int off = 32; off > 0; off >>= 1) {
      a0 += __shfl_down(a0, off); a1 += __shfl_down(a1, off);
      a2 += __shfl_down(a2, off); a3 += __shfl_down(a3, off);
    }
    if (lane == 0) {
      double l[4] = {a0, a1, a2, a3};
      int bi = 0; double mx = l[0];
      for (int k = 1; k < 4; k++) if (l[k] > mx) { mx = l[k]; bi = k; }
      double p[4], s = 0;
      for (int k = 0; k < 4; k++) { p[k] = exp(l[k] - mx); s += p[k]; }
      double inv = 1.0 / s, sq = 0, sp = 0;
      for (int k = 0; k < 4; k++) { p[k] *= inv; sq += p[k] * p[k]; sp += p[k]; }
      gval[t] = (float)p[bi];
      sgid[sl] = bi;
      double* vv = vals[sl];
      vv[0] = p[0]; vv[1] = p[1]; vv[2] = p[2]; vv[3] = p[3];
      vv[4] = sp / (sqrt(sq) + 1e-10);
    }
  }
  __syncthreads();
  if (threadIdx.x < 5) {
    double acc = 0;
    for (int k = 0; k < 64; k++) acc += vals[k][threadIdx.x];
    partials[(size_t)blockIdx.x * 5 + threadIdx.x] = acc;
  }
  if (threadIdx.x < 64) {
    const int e = sgid[threadIdx.x];
    const int t = blockIdx.x * 64 + threadIdx.x;
    for (int ei = 0; ei < NEXP; ei++) {
      unsigned long long mask = __ballot(e == ei);
      if (mask == 0ull) continue;
      const int leader = __ffsll((unsigned long long)mask) - 1;
      unsigned base = 0;
      if (lane == leader) base = atomicAdd(&counts[ei], (unsigned)__popcll(mask));
      base = __shfl(base, leader, 64);
      if (e == ei) {
        const int rank = __popcll(mask & ((1ull << lane) - 1ull));
        perm[(size_t)ei * NTOK + base + rank] = (unsigned)t;
      }
    }
  }
}

// ---------------- fused grouped expert FFN: 4-wave blocks, 2 blocks/CU ----------------
// LDS: Xs 64KB (frag units 1KB: unit = k16*2+mf, slot-permuted)
//      Hs 16KB (H-chunk 128: unit = k16h*2+mf)   total = 81920 (exactly 80KiB)
#define LDS_HS 65536
#define LDS_TOTAL 81920

__global__ __launch_bounds__(256, 2) void ffn_kernel(
    const float* __restrict__ x,
    const float* __restrict__ b1, const float* __restrict__ b2,
    const char* __restrict__ pw1, const char* __restrict__ pw2,
    const unsigned* __restrict__ counts, const unsigned* __restrict__ perm,
    const float* __restrict__ gval, const double* __restrict__ partials,
    float* __restrict__ out) {
  extern __shared__ char smem[];
  char* Xs = smem;
  char* Hs = smem + LDS_HS;

  const int tid = threadIdx.x;
  const int lane = tid & 63, wid = tid >> 6;           // 4 waves
  const int l31 = lane & 31, lh = lane >> 5;
  const unsigned sloff = (unsigned)(((((l31 >> 2) << 3) | ((l31 & 3) << 1) | lh)) << 4);

  const unsigned c0 = counts[0], c1 = counts[1], c2 = counts[2], c3 = counts[3];
  const unsigned n0 = (c0 + 63u) >> 6, n1 = (c1 + 63u) >> 6, n2 = (c2 + 63u) >> 6, n3 = (c3 + 63u) >> 6;
  const unsigned bs1 = n0, bs2 = n0 + n1, bs3 = n0 + n1 + n2, total = bs3 + n3;

  // XCD swizzle for nwg=512
  const unsigned orig = blockIdx.x;
  const unsigned wg = (orig & 7u) * 64u + (orig >> 3);

  // loss finalize (block 0, wave 0)
  if (orig == 0u && wid == 0) {
    double s0 = 0, s1 = 0, s2 = 0, s3 = 0, s4 = 0;
    for (int k = lane; k < 512; k += 64) {
      const double* p = partials + (size_t)k * 5;
      s0 += p[0]; s1 += p[1]; s2 += p[2]; s3 += p[3]; s4 += p[4];
    }
    for (int off = 32; off > 0; off >>= 1) {
      s0 += __shfl_down(s0, off); s1 += __shfl_down(s1, off);
      s2 += __shfl_down(s2, off); s3 += __shfl_down(s3, off);
      s4 += __shfl_down(s4, off);
    }
    if (lane == 0) {
      double mean = (s0 + s1 + s2 + s3) * 0.25;
      double var = ((s0 - mean) * (s0 - mean) + (s1 - mean) * (s1 - mean) +
                    (s2 - mean) * (s2 - mean) + (s3 - mean) * (s3 - mean)) * 0.25;
      out[16777216] = (float)(s4 / (double)NTOK);
      out[16777217] = (float)(var / (mean * mean + 1e-10));
    }
  }

  for (unsigned ti = wg; ti < total; ti += 512u) {
    int e; unsigned tb;
    if (ti >= bs3)      { e = 3; tb = bs3; }
    else if (ti >= bs2) { e = 2; tb = bs2; }
    else if (ti >= bs1) { e = 1; tb = bs1; }
    else                { e = 0; tb = 0;   }
    const unsigned cnt_e = (e == 0) ? c0 : (e == 1) ? c1 : (e == 2) ? c2 : c3;
    const unsigned trow0 = (ti - tb) * 64u;
    const int mcnt = (int)min(64u, cnt_e - trow0);
    const size_t pbase = (size_t)e * NTOK + trow0;
    const char* pw1e = pw1 + ((size_t)e << 20);
    const char* pw2e = pw2 + ((size_t)e << 20);

    __builtin_amdgcn_s_barrier();   // prev tile's LDS fully consumed

    // per-lane token/gate registers (row = lane)
    const unsigned tokr = perm[pbase + (unsigned)(lane < mcnt ? lane : (mcnt - 1))];
    const float gvr = gval[tokr];

    // stage X tile: f32 -> bf16 -> frag-layout LDS
    {
      const int r = tid >> 2, q4 = tid & 3;
      const unsigned tokS = perm[pbase + (unsigned)(r < mcnt ? r : mcnt - 1)];
      const float* src = x + (size_t)tokS * DIN;
      const int rm = r & 31, rh = r >> 5;
#pragma unroll
      for (int i = 0; i < 16; ++i) {
        const int g = i * 4 + q4;
        const float4 f0 = *(const float4*)(src + g * 8);
        const float4 f1 = *(const float4*)(src + g * 8 + 4);
        const int k16 = g >> 1, kh = g & 1;
        const unsigned slot = ((unsigned)(((rm >> 2) << 3) | ((rm & 3) << 1) | kh)) ^ ((unsigned)(k16 & 1) << 2);
        *(short8*)(Xs + (((k16 << 1) + rh) << 10) + (slot << 4)) = pack8(f0, f1);
      }
    }
    asm volatile("s_waitcnt lgkmcnt(0)" ::: "memory");
    __builtin_amdgcn_s_barrier();

    f32x16 acc2[2][4];
#pragma unroll
    for (int i = 0; i < 2; i++)
#pragma unroll
      for (int j = 0; j < 4; j++) acc2[i][j] = f32x16{};

    for (int hc = 0; hc < 8; ++hc) {
      // ---- GEMM1: acc1 (64 tok x 32 H-cols per wave) over k=512 ----
      f32x16 acc1_0 = f32x16{}, acc1_1 = f32x16{};
      const char* pB1 = pw1e + (((size_t)(hc * 4 + wid)) << 15) + (size_t)(lane << 4);
      short8 bc0 = *(const short8*)(pB1);
      short8 bc1 = *(const short8*)(pB1 + 1024);
#pragma unroll
      for (int blk = 0; blk < 16; ++blk) {
        short8 bn0 = bc0, bn1 = bc1;
        if (blk < 15) {
          bn0 = *(const short8*)(pB1 + (size_t)(((blk + 1) * 2 + 0) << 10));
          bn1 = *(const short8*)(pB1 + (size_t)(((blk + 1) * 2 + 1) << 10));
        }
        const int k0 = blk * 2, k1 = k0 + 1;
        const short8 a00 = *(const short8*)(Xs + ((k0 * 2 + 0) << 10) + sloff);
        const short8 a01 = *(const short8*)(Xs + ((k0 * 2 + 1) << 10) + sloff);
        const short8 a10 = *(const short8*)(Xs + ((k1 * 2 + 0) << 10) + (sloff ^ 64u));
        const short8 a11 = *(const short8*)(Xs + ((k1 * 2 + 1) << 10) + (sloff ^ 64u));
        __builtin_amdgcn_s_setprio(1);
        acc1_0 = mfma32(a00, bc0, acc1_0);
        acc1_1 = mfma32(a01, bc0, acc1_1);
        acc1_0 = mfma32(a10, bc1, acc1_0);
        acc1_1 = mfma32(a11, bc1, acc1_1);
        __builtin_amdgcn_s_setprio(0);
        bc0 = bn0; bc1 = bn1;
      }

      // prefetch GEMM2 kb=0 B-frags now (latency hides under barriers + Hs write)
      const char* pB2 = pw2e + (((size_t)wid) << 18) + (((size_t)(hc * 8)) << 10) + (size_t)(lane << 4);
      short8 cf0 = *(const short8*)(pB2);
      short8 cf1 = *(const short8*)(pB2 + (1 << 16));
      short8 cf2 = *(const short8*)(pB2 + (2 << 16));
      short8 cf3 = *(const short8*)(pB2 + (3 << 16));

      __builtin_amdgcn_s_barrier();   // all waves done reading Hs (prev hc)

      // ---- bias + relu -> Hs (frag layout, chunk 128) ----
      {
        const float bias = b1[e * HID + hc * 128 + wid * 32 + l31];
        const unsigned uBase = (unsigned)(wid * 2 + (l31 >> 4));   // c>>4
        const unsigned khh = (unsigned)((l31 >> 3) & 1);
        const unsigned xorb = (uBase & 1u) << 2;
        const unsigned cbyte = (unsigned)((l31 & 7) << 1);
#pragma unroll
        for (int mf = 0; mf < 2; ++mf) {
          const f32x16 av = mf ? acc1_1 : acc1_0;
#pragma unroll
          for (int v = 0; v < 16; ++v) {
            const int rv = (v & 3) + 8 * (v >> 2) + 4 * lh;
            float val = av[v] + bias;
            val = val > 0.f ? val : 0.f;
            const unsigned slot = (((unsigned)(rv >> 2) << 3) | (((unsigned)rv & 3) << 1) | khh) ^ xorb;
            *(unsigned short*)(Hs + (((uBase << 1) + (unsigned)mf) << 10) + (slot << 4) + cbyte) = f2bf(val);
          }
        }
      }
      asm volatile("s_waitcnt lgkmcnt(0)" ::: "memory");
      __builtin_amdgcn_s_barrier();

      // ---- GEMM2: acc2 += H_chunk(64x128) * W2chunk^T ----
#pragma unroll
      for (int kb = 0; kb < 8; ++kb) {
        short8 nf0 = cf0, nf1 = cf1, nf2 = cf2, nf3 = cf3;
        if (kb < 7) {
          nf0 = *(const short8*)(pB2 + (size_t)((kb + 1) << 10));
          nf1 = *(const short8*)(pB2 + (size_t)((1 << 16) + ((kb + 1) << 10)));
          nf2 = *(const short8*)(pB2 + (size_t)((2 << 16) + ((kb + 1) << 10)));
          nf3 = *(const short8*)(pB2 + (size_t)((3 << 16) + ((kb + 1) << 10)));
        }
        const unsigned xo = (unsigned)((kb & 1) << 6);
        const short8 h0 = *(const short8*)(Hs + ((kb * 2 + 0) << 10) + (sloff ^ xo));
        const short8 h1 = *(const short8*)(Hs + ((kb * 2 + 1) << 10) + (sloff ^ xo));
        __builtin_amdgcn_s_setprio(1);
        acc2[0][0] = mfma32(h0, cf0, acc2[0][0]);
        acc2[1][0] = mfma32(h1, cf0, acc2[1][0]);
        acc2[0][1] = mfma32(h0, cf1, acc2[0][1]);
        acc2[1][1] = mfma32(h1, cf1, acc2[1][1]);
        acc2[0][2] = mfma32(h0, cf2, acc2[0][2]);
        acc2[1][2] = mfma32(h1, cf2, acc2[1][2]);
        acc2[0][3] = mfma32(h0, cf3, acc2[0][3]);
        acc2[1][3] = mfma32(h1, cf3, acc2[1][3]);
        __builtin_amdgcn_s_setprio(0);
        cf0 = nf0; cf1 = nf1; cf2 = nf2; cf3 = nf3;
      }
    }

    // ---- epilogue: (y + b2) * gate -> out ----
    const float* b2e = b2 + e * DIN + wid * 128 + l31;
    const float bv0 = b2e[0], bv1 = b2e[32], bv2 = b2e[64], bv3 = b2e[96];
#pragma unroll
    for (int mf = 0; mf < 2; ++mf) {
#pragma unroll
      for (int v = 0; v < 16; ++v) {
        const int rv = (v & 3) + 8 * (v >> 2) + 4 * lh;
        const int R = mf * 32 + rv;
        const unsigned tk = (unsigned)__shfl((int)tokr, R);
        const float gv = __shfl(gvr, R);
        if (R < mcnt) {
          float* orow = out + (size_t)tk * DIN + wid * 128 + l31;
          orow[0]  = (acc2[mf][0][v] + bv0) * gv;
          orow[32] = (acc2[mf][1][v] + bv1) * gv;
          orow[64] = (acc2[mf][2][v] + bv2) * gv;
          orow[96] = (acc2[mf][3][v] + bv3) * gv;
        }
      }
    }
  }
}

extern "C" void kernel_launch(void* const* d_in, const int* in_sizes, int n_in,
                              void* d_out, int out_size, void* d_ws, size_t ws_size,
                              hipStream_t stream) {
  const float* x   = (const float*)d_in[0];
  const float* emb = (const float*)d_in[1];
  const float* rw  = (const float*)d_in[2];
  const float* w1  = (const float*)d_in[3];
  const float* b1  = (const float*)d_in[4];
  const float* w2  = (const float*)d_in[5];
  const float* b2  = (const float*)d_in[6];
  float* out = (float*)d_out;

  char* ws = (char*)d_ws;
  unsigned* counts = (unsigned*)(ws + OFF_COUNTS);
  float* gval = (float*)(ws + OFF_GVAL);
  unsigned* perm = (unsigned*)(ws + OFF_PERM);
  double* partials = (double*)(ws + OFF_PART);
  char* pw1 = ws + OFF_WB1;
  char* pw2 = ws + OFF_WB2;

  hipMemsetAsync(ws, 0, 256, stream);
  router_kernel<<<512, 256, 0, stream>>>(x, emb, rw, gval, counts, perm, partials,
                                         w1, w2, pw1, pw2);

  hipFuncSetAttribute((const void*)ffn_kernel, hipFuncAttributeMaxDynamicSharedMemorySize, LDS_TOTAL);
  ffn_kernel<<<512, 256, LDS_TOTAL, stream>>>(x, b1, b2, pw1, pw2, counts, perm, gval, partials, out);
}